// Round 16
// baseline (267.085 us; speedup 1.0000x reference)
//
#include <hip/hip_runtime.h>
#include <hip/hip_bf16.h>

#define NUM_EMB 1024
#define EMB_DIM 64
#define NPIX    131072                 // 32*64*64 pixels
#define ZQ_ELEMS 8388608               // NPIX * EMB_DIM
#define KDEPTH  16
#define ZSTRIDE 65                     // padded f32 LDS stride (conflict-free)
#define NACC    64                     // spread loss accumulators
#define BIAS    0.25f                  // makes screen scores positive (packable)
#define NBLK    (NPIX / 64)            // 2048 main-kernel blocks

// d_out FLOAT32: [ z_q (8388608, b-c-h-w) | loss (1) | enc (131072) ]
// d_ws: [ E'frag 128KB | e2 f32 4KB | lossAcc f32[64] @135168 | done @135424 ]

typedef __attribute__((ext_vector_type(8))) short short8_t;  // bf16x8 frag
typedef __attribute__((ext_vector_type(4))) float f32x4;     // mfma acc

__device__ __forceinline__ unsigned umin32(unsigned a, unsigned b) { return a < b ? a : b; }
__device__ __forceinline__ unsigned umax32(unsigned a, unsigned b) { return a > b ? a : b; }

// numpy pairwise-sum (n=64, 8-accumulator) of x[j]^2 — token-identical to the
// round-5..15 PASSING kernels (bit-matches np.sum(x**2, axis=-1)).
__device__ __forceinline__ float np_sumsq64(const float* __restrict__ x) {
    float q[EMB_DIM];
    #pragma unroll
    for (int c = 0; c < EMB_DIM; ++c) q[c] = x[c] * x[c];
    float r0 = q[0], r1 = q[1], r2 = q[2], r3 = q[3];
    float r4 = q[4], r5 = q[5], r6 = q[6], r7 = q[7];
    #pragma unroll
    for (int g = 1; g < 8; ++g) {
        r0 += q[8 * g + 0]; r1 += q[8 * g + 1];
        r2 += q[8 * g + 2]; r3 += q[8 * g + 3];
        r4 += q[8 * g + 4]; r5 += q[8 * g + 5];
        r6 += q[8 * g + 6]; r7 += q[8 * g + 7];
    }
    return ((r0 + r1) + (r2 + r3)) + ((r4 + r5) + (r6 + r7));
}

__device__ __forceinline__ unsigned long long packvk(float v, int k) {
    unsigned u = __float_as_uint(v);
    u = (u & 0x80000000u) ? ~u : (u | 0x80000000u);   // monotonic f32 -> u32
    return ((unsigned long long)u << 32) | (unsigned)k;
}

// Prep: E'frag + np-exact e2 + zero lossAcc/done (merged vq_zero).
__global__ __launch_bounds__(256) void vq_prep(const float* __restrict__ emb,
                                               short* __restrict__ wsE,
                                               float* __restrict__ wsE2,
                                               float* __restrict__ wsAcc,
                                               int* __restrict__ wsDone) {
    #pragma clang fp contract(off)
    int t    = blockIdx.x * 256 + threadIdx.x;    // grid = 16 x 256 = 4096
    if (blockIdx.x == 0) {
        if (threadIdx.x < NACC) wsAcc[threadIdx.x] = 0.f;
        if (threadIdx.x == 0) wsDone[0] = 0;
    }
    int l    = t & 63;
    int ch   = (t >> 6) & 15;
    int q    = t >> 10;
    int code = q * 256 + ch * 16 + (l & 15);
    const float* ek = emb + code * EMB_DIM;
    #pragma unroll
    for (int h = 0; h < 2; ++h) {
        short8_t pk;
        #pragma unroll
        for (int j = 0; j < 8; ++j) {
            int chan = 32 * h + 8 * (l >> 4) + j;
            __hip_bfloat16 bv = __float2bfloat16(-2.0f * ek[chan]);
            unsigned short u; __builtin_memcpy(&u, &bv, 2);
            pk[j] = (short)u;
        }
        *(short8_t*)(wsE + t * 16 + h * 8) = pk;
    }
    if (t < NUM_EMB) wsE2[t] = np_sumsq64(emb + t * EMB_DIM);
}

// ---------------------------------------------------------------------------
// Main: r15 structure (single screen pass, packed u32 top-3, flag->rare
// recollect, exact np-f32 eval). Deltas: no sE2b (bias added in-loop),
// launch_bounds(256,6), last-block-done loss finalize (no extra launches).
// ---------------------------------------------------------------------------
__global__ __launch_bounds__(256, 6) void vq_mfma(const float* __restrict__ z_e,
                                                  const float* __restrict__ emb,
                                                  const short* __restrict__ wsE,
                                                  const float* __restrict__ wsE2,
                                                  float* __restrict__ zq_out,
                                                  float* __restrict__ enc_out,
                                                  float* __restrict__ wsAcc,
                                                  int* __restrict__ wsDone,
                                                  float* __restrict__ loss_out) {
    #pragma clang fp contract(off)
    __shared__ float sZf[64 * ZSTRIDE];           // 16.6 KB exact f32 z tile
    __shared__ float sE2[NUM_EMB];                // 4 KB (unbiased)
    __shared__ unsigned sMinP[4][64];             // 1 KB packed wave mins
    __shared__ float sBand[64];
    __shared__ float sThrF[64];
    __shared__ unsigned sThrP[64];
    __shared__ float sZZ[64];
    __shared__ unsigned long long sBestPack[64];  // (mono(v)<<32)|k
    __shared__ unsigned short sKbuf[64][KDEPTH];  // 2 KB
    __shared__ int   sKcnt[64];
    __shared__ int   sPxFlag[64];
    __shared__ int   sFlagAny;
    __shared__ int   sIsLast;

    const int tid  = threadIdx.x;
    const int w    = tid >> 6;
    const int lane = tid & 63;
    const int p0   = blockIdx.x * 64;
    const int b    = p0 >> 12;                    // uniform (64 | 4096)
    const int hw0  = p0 & 4095;
    const float* base = z_e + (size_t)b * (EMB_DIM * 4096) + hw0;

    *(f32x4*)&sE2[tid * 4] = *(const f32x4*)&wsE2[tid * 4];
    if (tid < 64) { sKcnt[tid] = 0; sBestPack[tid] = ~0ULL; sPxFlag[tid] = 0; }
    if (tid == 0) sFlagAny = 0;

    // --- tile load: thread -> pixel lane, channels 16w..16w+15 (coalesced) ---
    {
        const float* zp = base + lane;
        float v[16];
        #pragma unroll
        for (int j = 0; j < 16; ++j) v[j] = zp[(size_t)(16 * w + j) * 4096];
        #pragma unroll
        for (int j = 0; j < 16; ++j) sZf[lane * ZSTRIDE + 16 * w + j] = v[j];
    }
    __syncthreads();                               // B1

    // --- wave0: np-exact zz + band from LDS (overlaps other waves) ---
    if (w == 0) {
        const float* zl = &sZf[lane * ZSTRIDE];
        float rr[8] = {0,0,0,0,0,0,0,0};
        float sab = 0.f;
        #pragma unroll
        for (int g = 0; g < 8; ++g)
            #pragma unroll
            for (int j = 0; j < 8; ++j) {
                float zc = zl[8 * g + j];
                float qq = zc * zc;               // separate mul (contract off)
                rr[j] += qq;                      // g-ascending per j = np order
                sab += fabsf(zc);
            }
        sZZ[lane]   = ((rr[0] + rr[1]) + (rr[2] + rr[3])) + ((rr[4] + rr[5]) + (rr[6] + rr[7]));
        // band guard: +1e-4 covers packed 10-bit mantissa quantization
        sBand[lane] = 2.0f * (9e-6f * sab + 2e-5f) + 1e-4f;
    }

    // --- B fragments from f32 LDS, then PIN in VGPRs (no LDS remat) ---
    short8_t bfrag[4][2];
    #pragma unroll
    for (int pg = 0; pg < 4; ++pg)
        #pragma unroll
        for (int h = 0; h < 2; ++h) {
            int bpr = pg * 16 + (lane & 15);
            int c0  = 32 * h + 8 * (lane >> 4);
            short8_t pk;
            #pragma unroll
            for (int j = 0; j < 8; ++j) {
                __hip_bfloat16 bv = __float2bfloat16(sZf[bpr * ZSTRIDE + c0 + j]);
                unsigned short u; __builtin_memcpy(&u, &bv, 2);
                pk[j] = (short)u;
            }
            asm volatile("" : "+v"(pk));          // force materialization
            bfrag[pg][h] = pk;
        }

    const short8_t* ef = (const short8_t*)wsE + (size_t)w * 2048;

    // ===== SINGLE SCREEN PASS: packed u32 top-3 per (lane,pg) =====
    unsigned p1[4] = {~0u, ~0u, ~0u, ~0u};
    unsigned p2[4] = {~0u, ~0u, ~0u, ~0u};
    unsigned p3[4] = {~0u, ~0u, ~0u, ~0u};
    {
        short8_t A0 = ef[lane * 2 + 0];
        short8_t A1 = ef[lane * 2 + 1];
        #pragma unroll 1
        for (int ch = 0; ch < 16; ++ch) {
            int chn = ch < 15 ? ch + 1 : 15;
            short8_t N0 = ef[(chn * 64 + lane) * 2 + 0];
            short8_t N1 = ef[(chn * 64 + lane) * 2 + 1];
            int kbase = w * 256 + ch * 16 + 4 * (lane >> 4);
            f32x4 e2v = *(const f32x4*)(&sE2[kbase]);
            f32x4 e2bv;
            e2bv[0] = e2v[0] + BIAS; e2bv[1] = e2v[1] + BIAS;
            e2bv[2] = e2v[2] + BIAS; e2bv[3] = e2v[3] + BIAS;
            unsigned kb[4] = {(unsigned)kbase, (unsigned)kbase + 1u,
                              (unsigned)kbase + 2u, (unsigned)kbase + 3u};
            #pragma unroll
            for (int pg = 0; pg < 4; ++pg) {
                f32x4 acc = __builtin_amdgcn_mfma_f32_16x16x32_bf16(A0, bfrag[pg][0], e2bv, 0, 0, 0);
                acc = __builtin_amdgcn_mfma_f32_16x16x32_bf16(A1, bfrag[pg][1], acc, 0, 0, 0);
                #pragma unroll
                for (int j = 0; j < 4; ++j) {
                    unsigned t  = (__float_as_uint(acc[j]) & 0xFFFFFC00u) | kb[j];
                    unsigned n1 = umin32(p1[pg], t);
                    unsigned x1 = umax32(p1[pg], t);
                    unsigned n2 = umin32(p2[pg], x1);
                    unsigned x2 = umax32(p2[pg], x1);
                    unsigned n3 = umin32(p3[pg], x2);
                    p1[pg] = n1; p2[pg] = n2; p3[pg] = n3;
                }
            }
            A0 = N0; A1 = N1;
        }
    }

    // per-pixel global packed min across lane-groups, then waves
    #pragma unroll
    for (int pg = 0; pg < 4; ++pg) {
        unsigned g = p1[pg];
        g = umin32(g, (unsigned)__shfl_xor((int)g, 16, 64));
        g = umin32(g, (unsigned)__shfl_xor((int)g, 32, 64));
        if (lane < 16) sMinP[w][pg * 16 + lane] = g;
    }
    __syncthreads();                               // B2
    if (tid < 64) {
        unsigned gp = umin32(umin32(sMinP[0][tid], sMinP[1][tid]),
                             umin32(sMinP[2][tid], sMinP[3][tid]));
        float m    = __uint_as_float(gp & 0xFFFFFC00u);
        float thrF = m + sBand[tid];
        sThrF[tid] = thrF;
        sThrP[tid] = (__float_as_uint(thrF) & 0xFFFFFC00u) | 1023u;
    }
    __syncthreads();                               // B3

    // ===== EMIT: lane emits its top-3 packed entries <= thr; flag on p3 =====
    #pragma unroll
    for (int pg = 0; pg < 4; ++pg) {
        int px = pg * 16 + (lane & 15);
        unsigned thrp = sThrP[px];
        if (p1[pg] <= thrp) {
            int slot = atomicAdd(&sKcnt[px], 1);
            if (slot < KDEPTH) sKbuf[px][slot] = (unsigned short)(p1[pg] & 1023u);
        }
        if (p2[pg] <= thrp) {
            int slot = atomicAdd(&sKcnt[px], 1);
            if (slot < KDEPTH) sKbuf[px][slot] = (unsigned short)(p2[pg] & 1023u);
        }
        if (p3[pg] <= thrp) {                      // lane may have dropped a 4th
            int slot = atomicAdd(&sKcnt[px], 1);
            if (slot < KDEPTH) sKbuf[px][slot] = (unsigned short)(p3[pg] & 1023u);
            sPxFlag[px] = 1; sFlagAny = 1;
        }
    }
    __syncthreads();                               // B4

    // ===== RARE: flagged pixels -> full recollect (biased f32 compare) =====
    if (sFlagAny) {
        if (tid < 64 && sPxFlag[tid]) sKcnt[tid] = 0;
        __syncthreads();
        float thrB[4];
        #pragma unroll
        for (int pg = 0; pg < 4; ++pg) {
            int px = pg * 16 + (lane & 15);
            thrB[pg] = sPxFlag[px] ? sThrF[px] : -1e30f;
        }
        short8_t A0 = ef[lane * 2 + 0];
        short8_t A1 = ef[lane * 2 + 1];
        #pragma unroll 1
        for (int ch = 0; ch < 16; ++ch) {
            int chn = ch < 15 ? ch + 1 : 15;
            short8_t N0 = ef[(chn * 64 + lane) * 2 + 0];
            short8_t N1 = ef[(chn * 64 + lane) * 2 + 1];
            int kbase = w * 256 + ch * 16 + 4 * (lane >> 4);
            f32x4 e2v = *(const f32x4*)(&sE2[kbase]);
            f32x4 e2bv;
            e2bv[0] = e2v[0] + BIAS; e2bv[1] = e2v[1] + BIAS;
            e2bv[2] = e2v[2] + BIAS; e2bv[3] = e2v[3] + BIAS;
            #pragma unroll
            for (int pg = 0; pg < 4; ++pg) {
                f32x4 acc = __builtin_amdgcn_mfma_f32_16x16x32_bf16(A0, bfrag[pg][0], e2bv, 0, 0, 0);
                acc = __builtin_amdgcn_mfma_f32_16x16x32_bf16(A1, bfrag[pg][1], acc, 0, 0, 0);
                #pragma unroll
                for (int j = 0; j < 4; ++j) {
                    if (acc[j] <= thrB[pg]) {
                        int pix  = pg * 16 + (lane & 15);
                        int slot = atomicAdd(&sKcnt[pix], 1);
                        if (slot < KDEPTH) sKbuf[pix][slot] = (unsigned short)(kbase + j);
                    }
                }
            }
            A0 = N0; A1 = N1;
        }
        __syncthreads();
    }

    // ===== EXACT EVAL: 4 threads/pixel; rawcnt==1 certified shortcut =====
    {
        const int px = lane;
        const float* zl = &sZf[px * ZSTRIDE];
        float zzv = sZZ[px];
        int rawcnt = sKcnt[px];
        if (rawcnt == 1) {
            if (w == 0) sBestPack[px] = packvk(-1e30f, (int)sKbuf[px][0]);
        } else if (rawcnt <= KDEPTH) {
            for (int s = w; s < rawcnt; s += 4) {
                int k = (int)sKbuf[px][s];
                const float* ek = emb + k * EMB_DIM;
                float acc = 0.f;
                #pragma unroll 8
                for (int c = 0; c < EMB_DIM; ++c)   // sequential fmaf = BLAS order
                    acc = fmaf(ek[c], zl[c], acc);
                float v = (zzv + sE2[k]) - 2.0f * acc;  // exact np token sequence
                atomicMin(&sBestPack[px], packvk(v, k));
            }
        } else {                                   // overflow safety net (~never)
            for (int k = w; k < NUM_EMB; k += 4) {
                const float* ek = emb + k * EMB_DIM;
                float acc = 0.f;
                #pragma unroll 8
                for (int c = 0; c < EMB_DIM; ++c)
                    acc = fmaf(ek[c], zl[c], acc);
                float v = (zzv + sE2[k]) - 2.0f * acc;
                atomicMin(&sBestPack[px], packvk(v, k));
            }
        }
    }
    __syncthreads();

    // ===== enc + epilogue (z from LDS; coalesced z_q stores) =====
    if (tid < 64)
        enc_out[p0 + tid] = (float)(unsigned)(sBestPack[tid] & 0xFFFFFFFFull);
    {
        const int px = lane;
        int bestk = (int)(sBestPack[px] & 0xFFFFFFFFull);
        const float* eq = emb + bestk * EMB_DIM;
        const float* zl = &sZf[px * ZSTRIDE];
        float* op = zq_out + (size_t)b * (EMB_DIM * 4096) + hw0 + px;
        float ls = 0.f;
        #pragma unroll
        for (int j = 0; j < 16; ++j) {
            int c = 16 * w + j;
            float qv = eq[c];
            float d = qv - zl[c];
            ls = fmaf(d, d, ls);
            op[(size_t)c * 4096] = qv;
        }
        #pragma unroll
        for (int off = 32; off > 0; off >>= 1) ls += __shfl_down(ls, off, 64);
        if (lane == 0) atomicAdd(&wsAcc[blockIdx.x & (NACC - 1)], ls);
    }

    // ===== last-block-done loss finalize (replaces vq_final launch) =====
    __threadfence();                               // publish wsAcc add
    if (tid == 0) sIsLast = (atomicAdd(wsDone, 1) == NBLK - 1);
    __syncthreads();
    if (sIsLast && w == 0) {
        __threadfence();                           // acquire all wsAcc adds
        float v = wsAcc[lane];
        #pragma unroll
        for (int off = 32; off > 0; off >>= 1) v += __shfl_down(v, off, 64);
        if (lane == 0) loss_out[0] = v * (1.25f / (float)ZQ_ELEMS);
    }
}

// ---------- fallback (round-6 passing kernel) if d_ws is too small ----------
__global__ void vq_final_direct(float* __restrict__ loss_out) {
    loss_out[0] = loss_out[0] * (1.25f / (float)ZQ_ELEMS);
}

__global__ __launch_bounds__(256) void vq_nn_fb(const float* __restrict__ z_e,
                                                const float* __restrict__ emb,
                                                float* __restrict__ zq_out,
                                                float* __restrict__ enc_out,
                                                float* __restrict__ loss_acc) {
    #pragma clang fp contract(off)
    __shared__ float s_e2[NUM_EMB];
    int tid = threadIdx.x;
    for (int k = tid; k < NUM_EMB; k += 256) s_e2[k] = np_sumsq64(emb + k * EMB_DIM);
    __syncthreads();
    int p = blockIdx.x * 256 + tid;
    int b = p >> 12, hw = p & 4095;
    const float* zp = z_e + (size_t)b * (EMB_DIM * 4096) + hw;
    float z[EMB_DIM];
    #pragma unroll
    for (int c = 0; c < EMB_DIM; ++c) z[c] = zp[(size_t)c * 4096];
    float zz = np_sumsq64(z);
    float b1 = 3.4e38f; int i1 = 0;
    #pragma unroll 2
    for (int k = 0; k < NUM_EMB; ++k) {
        const float* ek = emb + k * EMB_DIM;
        float acc = 0.f;
        #pragma unroll
        for (int c = 0; c < EMB_DIM; ++c) acc = fmaf(ek[c], z[c], acc);
        float sc = (zz + s_e2[k]) - 2.0f * acc;
        bool lt = sc < b1; b1 = lt ? sc : b1; i1 = lt ? k : i1;
    }
    const float* eq = emb + i1 * EMB_DIM;
    float* op = zq_out + (size_t)b * (EMB_DIM * 4096) + hw;
    float ls = 0.f;
    #pragma unroll
    for (int c = 0; c < EMB_DIM; ++c) {
        float q = eq[c]; float d = q - z[c];
        ls = fmaf(d, d, ls);
        op[(size_t)c * 4096] = q;
    }
    enc_out[p] = (float)i1;
    #pragma unroll
    for (int off = 32; off > 0; off >>= 1) ls += __shfl_down(ls, off, 64);
    if ((tid & 63) == 0) atomicAdd(loss_acc, ls);
}

extern "C" void kernel_launch(void* const* d_in, const int* in_sizes, int n_in,
                              void* d_out, int out_size, void* d_ws, size_t ws_size,
                              hipStream_t stream) {
    const float* z_e = (const float*)d_in[0];
    const float* emb = (const float*)d_in[1];
    float* out = (float*)d_out;
    float* loss_out = out + ZQ_ELEMS;
    float* enc_out  = out + ZQ_ELEMS + 1;

    if (ws_size >= 140 * 1024) {
        short* wsE   = (short*)d_ws;                       // 128 KB frag-order
        float* wsE2  = (float*)((char*)d_ws + 131072);     // 4 KB
        float* wsAcc = (float*)((char*)d_ws + 135168);     // 256 B
        int*   wsDone= (int*)  ((char*)d_ws + 135424);     // 4 B
        vq_prep<<<16, 256, 0, stream>>>(emb, wsE, wsE2, wsAcc, wsDone);
        vq_mfma<<<NBLK, 256, 0, stream>>>(z_e, emb, wsE, wsE2, out, enc_out,
                                          wsAcc, wsDone, loss_out);
    } else {
        hipMemsetAsync(loss_out, 0, 4, stream);
        vq_nn_fb<<<NPIX / 256, 256, 0, stream>>>(z_e, emb, out, enc_out, loss_out);
        vq_final_direct<<<1, 1, 0, stream>>>(loss_out);
    }
}

// Round 17
// 86.746 us; speedup vs baseline: 3.0789x; 3.0789x over previous
//
#include <hip/hip_runtime.h>
#include <hip/hip_bf16.h>

#define NUM_EMB 1024
#define EMB_DIM 64
#define NPIX    131072                 // 32*64*64 pixels
#define ZQ_ELEMS 8388608               // NPIX * EMB_DIM
#define KDEPTH  16
#define ZSTRIDE 65                     // padded f32 LDS stride (conflict-free)
#define NACC    64                     // spread loss accumulators
#define BIAS    0.25f                  // makes screen scores positive (packable)

// d_out FLOAT32: [ z_q (8388608, b-c-h-w) | loss (1) | enc (131072) ]
// d_ws: [ E'frag 128KB | e2 f32 4KB | lossAcc f32[64] @135168 ]

typedef __attribute__((ext_vector_type(8))) short short8_t;  // bf16x8 frag
typedef __attribute__((ext_vector_type(4))) float f32x4;     // mfma acc

__device__ __forceinline__ unsigned umin32(unsigned a, unsigned b) { return a < b ? a : b; }
__device__ __forceinline__ unsigned umax32(unsigned a, unsigned b) { return a > b ? a : b; }

// numpy pairwise-sum (n=64, 8-accumulator) of x[j]^2 — token-identical to the
// round-5..15 PASSING kernels (bit-matches np.sum(x**2, axis=-1)).
__device__ __forceinline__ float np_sumsq64(const float* __restrict__ x) {
    float q[EMB_DIM];
    #pragma unroll
    for (int c = 0; c < EMB_DIM; ++c) q[c] = x[c] * x[c];
    float r0 = q[0], r1 = q[1], r2 = q[2], r3 = q[3];
    float r4 = q[4], r5 = q[5], r6 = q[6], r7 = q[7];
    #pragma unroll
    for (int g = 1; g < 8; ++g) {
        r0 += q[8 * g + 0]; r1 += q[8 * g + 1];
        r2 += q[8 * g + 2]; r3 += q[8 * g + 3];
        r4 += q[8 * g + 4]; r5 += q[8 * g + 5];
        r6 += q[8 * g + 6]; r7 += q[8 * g + 7];
    }
    return ((r0 + r1) + (r2 + r3)) + ((r4 + r5) + (r6 + r7));
}

__device__ __forceinline__ unsigned long long packvk(float v, int k) {
    unsigned u = __float_as_uint(v);
    u = (u & 0x80000000u) ? ~u : (u | 0x80000000u);   // monotonic f32 -> u32
    return ((unsigned long long)u << 32) | (unsigned)k;
}

// Prep: E'frag + np-exact e2 + zero wsAcc (merged vq_zero; no fences).
__global__ __launch_bounds__(256) void vq_prep(const float* __restrict__ emb,
                                               short* __restrict__ wsE,
                                               float* __restrict__ wsE2,
                                               float* __restrict__ wsAcc) {
    #pragma clang fp contract(off)
    int t    = blockIdx.x * 256 + threadIdx.x;    // grid = 16 x 256 = 4096
    if (blockIdx.x == 0 && threadIdx.x < NACC) wsAcc[threadIdx.x] = 0.f;
    int l    = t & 63;
    int ch   = (t >> 6) & 15;
    int q    = t >> 10;
    int code = q * 256 + ch * 16 + (l & 15);
    const float* ek = emb + code * EMB_DIM;
    #pragma unroll
    for (int h = 0; h < 2; ++h) {
        short8_t pk;
        #pragma unroll
        for (int j = 0; j < 8; ++j) {
            int chan = 32 * h + 8 * (l >> 4) + j;
            __hip_bfloat16 bv = __float2bfloat16(-2.0f * ek[chan]);
            unsigned short u; __builtin_memcpy(&u, &bv, 2);
            pk[j] = (short)u;
        }
        *(short8_t*)(wsE + t * 16 + h * 8) = pk;
    }
    if (t < NUM_EMB) wsE2[t] = np_sumsq64(emb + t * EMB_DIM);
}

// ---------------------------------------------------------------------------
// Main: r15 structure verbatim (single screen pass, packed u32 top-3,
// flag->rare recollect, exact np-f32 eval, lb(256,4)). Delta vs r15: sE2b
// removed — biased C-init computed in-loop (r16-proven numerics), LDS -4KB.
// ---------------------------------------------------------------------------
__global__ __launch_bounds__(256, 4) void vq_mfma(const float* __restrict__ z_e,
                                                  const float* __restrict__ emb,
                                                  const short* __restrict__ wsE,
                                                  const float* __restrict__ wsE2,
                                                  float* __restrict__ zq_out,
                                                  float* __restrict__ enc_out,
                                                  float* __restrict__ wsAcc) {
    #pragma clang fp contract(off)
    __shared__ float sZf[64 * ZSTRIDE];           // 16.6 KB exact f32 z tile
    __shared__ float sE2[NUM_EMB];                // 4 KB (unbiased)
    __shared__ unsigned sMinP[4][64];             // 1 KB packed wave mins
    __shared__ float sBand[64];
    __shared__ float sThrF[64];
    __shared__ unsigned sThrP[64];
    __shared__ float sZZ[64];
    __shared__ unsigned long long sBestPack[64];  // (mono(v)<<32)|k
    __shared__ unsigned short sKbuf[64][KDEPTH];  // 2 KB
    __shared__ int   sKcnt[64];
    __shared__ int   sPxFlag[64];
    __shared__ int   sFlagAny;

    const int tid  = threadIdx.x;
    const int w    = tid >> 6;
    const int lane = tid & 63;
    const int p0   = blockIdx.x * 64;
    const int b    = p0 >> 12;                    // uniform (64 | 4096)
    const int hw0  = p0 & 4095;
    const float* base = z_e + (size_t)b * (EMB_DIM * 4096) + hw0;

    *(f32x4*)&sE2[tid * 4] = *(const f32x4*)&wsE2[tid * 4];
    if (tid < 64) { sKcnt[tid] = 0; sBestPack[tid] = ~0ULL; sPxFlag[tid] = 0; }
    if (tid == 0) sFlagAny = 0;

    // --- tile load: thread -> pixel lane, channels 16w..16w+15 (coalesced) ---
    {
        const float* zp = base + lane;
        float v[16];
        #pragma unroll
        for (int j = 0; j < 16; ++j) v[j] = zp[(size_t)(16 * w + j) * 4096];
        #pragma unroll
        for (int j = 0; j < 16; ++j) sZf[lane * ZSTRIDE + 16 * w + j] = v[j];
    }
    __syncthreads();                               // B1

    // --- wave0: np-exact zz + band from LDS (overlaps other waves) ---
    if (w == 0) {
        const float* zl = &sZf[lane * ZSTRIDE];
        float rr[8] = {0,0,0,0,0,0,0,0};
        float sab = 0.f;
        #pragma unroll
        for (int g = 0; g < 8; ++g)
            #pragma unroll
            for (int j = 0; j < 8; ++j) {
                float zc = zl[8 * g + j];
                float qq = zc * zc;               // separate mul (contract off)
                rr[j] += qq;                      // g-ascending per j = np order
                sab += fabsf(zc);
            }
        sZZ[lane]   = ((rr[0] + rr[1]) + (rr[2] + rr[3])) + ((rr[4] + rr[5]) + (rr[6] + rr[7]));
        // band guard: +1e-4 covers packed 10-bit mantissa quantization
        sBand[lane] = 2.0f * (9e-6f * sab + 2e-5f) + 1e-4f;
    }

    // --- B fragments from f32 LDS, then PIN in VGPRs (no LDS remat) ---
    short8_t bfrag[4][2];
    #pragma unroll
    for (int pg = 0; pg < 4; ++pg)
        #pragma unroll
        for (int h = 0; h < 2; ++h) {
            int bpr = pg * 16 + (lane & 15);
            int c0  = 32 * h + 8 * (lane >> 4);
            short8_t pk;
            #pragma unroll
            for (int j = 0; j < 8; ++j) {
                __hip_bfloat16 bv = __float2bfloat16(sZf[bpr * ZSTRIDE + c0 + j]);
                unsigned short u; __builtin_memcpy(&u, &bv, 2);
                pk[j] = (short)u;
            }
            asm volatile("" : "+v"(pk));          // force materialization
            bfrag[pg][h] = pk;
        }

    const short8_t* ef = (const short8_t*)wsE + (size_t)w * 2048;

    // ===== SINGLE SCREEN PASS: packed u32 top-3 per (lane,pg) =====
    unsigned p1[4] = {~0u, ~0u, ~0u, ~0u};
    unsigned p2[4] = {~0u, ~0u, ~0u, ~0u};
    unsigned p3[4] = {~0u, ~0u, ~0u, ~0u};
    {
        short8_t A0 = ef[lane * 2 + 0];
        short8_t A1 = ef[lane * 2 + 1];
        #pragma unroll 1
        for (int ch = 0; ch < 16; ++ch) {
            int chn = ch < 15 ? ch + 1 : 15;
            short8_t N0 = ef[(chn * 64 + lane) * 2 + 0];
            short8_t N1 = ef[(chn * 64 + lane) * 2 + 1];
            int kbase = w * 256 + ch * 16 + 4 * (lane >> 4);
            f32x4 e2v = *(const f32x4*)(&sE2[kbase]);
            f32x4 e2bv;
            e2bv[0] = e2v[0] + BIAS; e2bv[1] = e2v[1] + BIAS;
            e2bv[2] = e2v[2] + BIAS; e2bv[3] = e2v[3] + BIAS;
            unsigned kb[4] = {(unsigned)kbase, (unsigned)kbase + 1u,
                              (unsigned)kbase + 2u, (unsigned)kbase + 3u};
            #pragma unroll
            for (int pg = 0; pg < 4; ++pg) {
                f32x4 acc = __builtin_amdgcn_mfma_f32_16x16x32_bf16(A0, bfrag[pg][0], e2bv, 0, 0, 0);
                acc = __builtin_amdgcn_mfma_f32_16x16x32_bf16(A1, bfrag[pg][1], acc, 0, 0, 0);
                #pragma unroll
                for (int j = 0; j < 4; ++j) {
                    unsigned t  = (__float_as_uint(acc[j]) & 0xFFFFFC00u) | kb[j];
                    unsigned n1 = umin32(p1[pg], t);
                    unsigned x1 = umax32(p1[pg], t);
                    unsigned n2 = umin32(p2[pg], x1);
                    unsigned x2 = umax32(p2[pg], x1);
                    unsigned n3 = umin32(p3[pg], x2);
                    p1[pg] = n1; p2[pg] = n2; p3[pg] = n3;
                }
            }
            A0 = N0; A1 = N1;
        }
    }

    // per-pixel global packed min across lane-groups, then waves
    #pragma unroll
    for (int pg = 0; pg < 4; ++pg) {
        unsigned g = p1[pg];
        g = umin32(g, (unsigned)__shfl_xor((int)g, 16, 64));
        g = umin32(g, (unsigned)__shfl_xor((int)g, 32, 64));
        if (lane < 16) sMinP[w][pg * 16 + lane] = g;
    }
    __syncthreads();                               // B2
    if (tid < 64) {
        unsigned gp = umin32(umin32(sMinP[0][tid], sMinP[1][tid]),
                             umin32(sMinP[2][tid], sMinP[3][tid]));
        float m    = __uint_as_float(gp & 0xFFFFFC00u);
        float thrF = m + sBand[tid];
        sThrF[tid] = thrF;
        sThrP[tid] = (__float_as_uint(thrF) & 0xFFFFFC00u) | 1023u;
    }
    __syncthreads();                               // B3

    // ===== EMIT: lane emits its top-3 packed entries <= thr; flag on p3 =====
    #pragma unroll
    for (int pg = 0; pg < 4; ++pg) {
        int px = pg * 16 + (lane & 15);
        unsigned thrp = sThrP[px];
        if (p1[pg] <= thrp) {
            int slot = atomicAdd(&sKcnt[px], 1);
            if (slot < KDEPTH) sKbuf[px][slot] = (unsigned short)(p1[pg] & 1023u);
        }
        if (p2[pg] <= thrp) {
            int slot = atomicAdd(&sKcnt[px], 1);
            if (slot < KDEPTH) sKbuf[px][slot] = (unsigned short)(p2[pg] & 1023u);
        }
        if (p3[pg] <= thrp) {                      // lane may have dropped a 4th
            int slot = atomicAdd(&sKcnt[px], 1);
            if (slot < KDEPTH) sKbuf[px][slot] = (unsigned short)(p3[pg] & 1023u);
            sPxFlag[px] = 1; sFlagAny = 1;
        }
    }
    __syncthreads();                               // B4

    // ===== RARE: flagged pixels -> full recollect (biased f32 compare) =====
    if (sFlagAny) {
        if (tid < 64 && sPxFlag[tid]) sKcnt[tid] = 0;
        __syncthreads();
        float thrB[4];
        #pragma unroll
        for (int pg = 0; pg < 4; ++pg) {
            int px = pg * 16 + (lane & 15);
            thrB[pg] = sPxFlag[px] ? sThrF[px] : -1e30f;
        }
        short8_t A0 = ef[lane * 2 + 0];
        short8_t A1 = ef[lane * 2 + 1];
        #pragma unroll 1
        for (int ch = 0; ch < 16; ++ch) {
            int chn = ch < 15 ? ch + 1 : 15;
            short8_t N0 = ef[(chn * 64 + lane) * 2 + 0];
            short8_t N1 = ef[(chn * 64 + lane) * 2 + 1];
            int kbase = w * 256 + ch * 16 + 4 * (lane >> 4);
            f32x4 e2v = *(const f32x4*)(&sE2[kbase]);
            f32x4 e2bv;
            e2bv[0] = e2v[0] + BIAS; e2bv[1] = e2v[1] + BIAS;
            e2bv[2] = e2v[2] + BIAS; e2bv[3] = e2v[3] + BIAS;
            #pragma unroll
            for (int pg = 0; pg < 4; ++pg) {
                f32x4 acc = __builtin_amdgcn_mfma_f32_16x16x32_bf16(A0, bfrag[pg][0], e2bv, 0, 0, 0);
                acc = __builtin_amdgcn_mfma_f32_16x16x32_bf16(A1, bfrag[pg][1], acc, 0, 0, 0);
                #pragma unroll
                for (int j = 0; j < 4; ++j) {
                    if (acc[j] <= thrB[pg]) {
                        int pix  = pg * 16 + (lane & 15);
                        int slot = atomicAdd(&sKcnt[pix], 1);
                        if (slot < KDEPTH) sKbuf[pix][slot] = (unsigned short)(kbase + j);
                    }
                }
            }
            A0 = N0; A1 = N1;
        }
        __syncthreads();
    }

    // ===== EXACT EVAL: 4 threads/pixel; rawcnt==1 certified shortcut =====
    {
        const int px = lane;
        const float* zl = &sZf[px * ZSTRIDE];
        float zzv = sZZ[px];
        int rawcnt = sKcnt[px];
        if (rawcnt == 1) {
            if (w == 0) sBestPack[px] = packvk(-1e30f, (int)sKbuf[px][0]);
        } else if (rawcnt <= KDEPTH) {
            for (int s = w; s < rawcnt; s += 4) {
                int k = (int)sKbuf[px][s];
                const float* ek = emb + k * EMB_DIM;
                float acc = 0.f;
                #pragma unroll 8
                for (int c = 0; c < EMB_DIM; ++c)   // sequential fmaf = BLAS order
                    acc = fmaf(ek[c], zl[c], acc);
                float v = (zzv + sE2[k]) - 2.0f * acc;  // exact np token sequence
                atomicMin(&sBestPack[px], packvk(v, k));
            }
        } else {                                   // overflow safety net (~never)
            for (int k = w; k < NUM_EMB; k += 4) {
                const float* ek = emb + k * EMB_DIM;
                float acc = 0.f;
                #pragma unroll 8
                for (int c = 0; c < EMB_DIM; ++c)
                    acc = fmaf(ek[c], zl[c], acc);
                float v = (zzv + sE2[k]) - 2.0f * acc;
                atomicMin(&sBestPack[px], packvk(v, k));
            }
        }
    }
    __syncthreads();

    // ===== enc + epilogue (z from LDS; coalesced z_q stores) =====
    if (tid < 64)
        enc_out[p0 + tid] = (float)(unsigned)(sBestPack[tid] & 0xFFFFFFFFull);
    {
        const int px = lane;
        int bestk = (int)(sBestPack[px] & 0xFFFFFFFFull);
        const float* eq = emb + bestk * EMB_DIM;
        const float* zl = &sZf[px * ZSTRIDE];
        float* op = zq_out + (size_t)b * (EMB_DIM * 4096) + hw0 + px;
        float ls = 0.f;
        #pragma unroll
        for (int j = 0; j < 16; ++j) {
            int c = 16 * w + j;
            float qv = eq[c];
            float d = qv - zl[c];
            ls = fmaf(d, d, ls);
            op[(size_t)c * 4096] = qv;
        }
        #pragma unroll
        for (int off = 32; off > 0; off >>= 1) ls += __shfl_down(ls, off, 64);
        if (lane == 0) atomicAdd(&wsAcc[blockIdx.x & (NACC - 1)], ls);
    }
}

__global__ void vq_final_ws(const float* __restrict__ wsAcc,
                            float* __restrict__ loss_out) {
    int lane = threadIdx.x;                       // 64 threads
    float v = wsAcc[lane];
    #pragma unroll
    for (int off = 32; off > 0; off >>= 1) v += __shfl_down(v, off, 64);
    if (lane == 0) loss_out[0] = v * (1.25f / (float)ZQ_ELEMS);
}

__global__ void vq_final_direct(float* __restrict__ loss_out) {
    loss_out[0] = loss_out[0] * (1.25f / (float)ZQ_ELEMS);
}

// ---------- fallback (round-6 passing kernel) if d_ws is too small ----------
__global__ __launch_bounds__(256) void vq_nn_fb(const float* __restrict__ z_e,
                                                const float* __restrict__ emb,
                                                float* __restrict__ zq_out,
                                                float* __restrict__ enc_out,
                                                float* __restrict__ loss_acc) {
    #pragma clang fp contract(off)
    __shared__ float s_e2[NUM_EMB];
    int tid = threadIdx.x;
    for (int k = tid; k < NUM_EMB; k += 256) s_e2[k] = np_sumsq64(emb + k * EMB_DIM);
    __syncthreads();
    int p = blockIdx.x * 256 + tid;
    int b = p >> 12, hw = p & 4095;
    const float* zp = z_e + (size_t)b * (EMB_DIM * 4096) + hw;
    float z[EMB_DIM];
    #pragma unroll
    for (int c = 0; c < EMB_DIM; ++c) z[c] = zp[(size_t)c * 4096];
    float zz = np_sumsq64(z);
    float b1 = 3.4e38f; int i1 = 0;
    #pragma unroll 2
    for (int k = 0; k < NUM_EMB; ++k) {
        const float* ek = emb + k * EMB_DIM;
        float acc = 0.f;
        #pragma unroll
        for (int c = 0; c < EMB_DIM; ++c) acc = fmaf(ek[c], z[c], acc);
        float sc = (zz + s_e2[k]) - 2.0f * acc;
        bool lt = sc < b1; b1 = lt ? sc : b1; i1 = lt ? k : i1;
    }
    const float* eq = emb + i1 * EMB_DIM;
    float* op = zq_out + (size_t)b * (EMB_DIM * 4096) + hw;
    float ls = 0.f;
    #pragma unroll
    for (int c = 0; c < EMB_DIM; ++c) {
        float q = eq[c]; float d = q - z[c];
        ls = fmaf(d, d, ls);
        op[(size_t)c * 4096] = q;
    }
    enc_out[p] = (float)i1;
    #pragma unroll
    for (int off = 32; off > 0; off >>= 1) ls += __shfl_down(ls, off, 64);
    if ((tid & 63) == 0) atomicAdd(loss_acc, ls);
}

extern "C" void kernel_launch(void* const* d_in, const int* in_sizes, int n_in,
                              void* d_out, int out_size, void* d_ws, size_t ws_size,
                              hipStream_t stream) {
    const float* z_e = (const float*)d_in[0];
    const float* emb = (const float*)d_in[1];
    float* out = (float*)d_out;
    float* loss_out = out + ZQ_ELEMS;
    float* enc_out  = out + ZQ_ELEMS + 1;

    if (ws_size >= 140 * 1024) {
        short* wsE   = (short*)d_ws;                       // 128 KB frag-order
        float* wsE2  = (float*)((char*)d_ws + 131072);     // 4 KB
        float* wsAcc = (float*)((char*)d_ws + 135168);     // 256 B
        vq_prep<<<16, 256, 0, stream>>>(emb, wsE, wsE2, wsAcc);
        vq_mfma<<<NPIX / 64, 256, 0, stream>>>(z_e, emb, wsE, wsE2, out, enc_out, wsAcc);
        vq_final_ws<<<1, 64, 0, stream>>>(wsAcc, loss_out);
    } else {
        hipMemsetAsync(loss_out, 0, 4, stream);
        vq_nn_fb<<<NPIX / 256, 256, 0, stream>>>(z_e, emb, out, enc_out, loss_out);
        vq_final_direct<<<1, 1, 0, stream>>>(loss_out);
    }
}